// Round 2
// baseline (19826.953 us; speedup 1.0000x reference)
//
#include <hip/hip_runtime.h>

typedef __attribute__((ext_vector_type(8))) short short8;
typedef __attribute__((ext_vector_type(4))) float f32x4;

#define MFMA_B16(a, b, c) __builtin_amdgcn_mfma_f32_16x16x32_bf16((a), (b), (c), 0, 0, 0)

#define TSTEPS 256
#define NBATCH 64
#define HID    512
#define NBLK   32   // blocks per direction
#define UB     16   // hidden units per block
#define HSLOT  (NBATCH * HID)  // shorts per h slot per dir

__device__ __forceinline__ unsigned short f2bf(float f) {
  unsigned int u = __float_as_uint(f);
  u += 0x7fffu + ((u >> 16) & 1u);
  return (unsigned short)(u >> 16);
}
__device__ __forceinline__ float bf2f(unsigned short s) {
  return __uint_as_float(((unsigned int)s) << 16);
}
__device__ __forceinline__ float sigm(float x) { return 1.0f / (1.0f + __expf(-x)); }
__device__ __forceinline__ float tanhf_(float x) {
  float xc = fminf(fmaxf(x, -15.0f), 15.0f);
  float e = __expf(2.0f * xc);
  return (e - 1.0f) / (e + 1.0f);
}

// 16B load from the coherent point (bypasses stale L1/L2), relaxed
__device__ __forceinline__ short8 ld_llc16(const unsigned short* p) {
  union { unsigned long long q[2]; short8 s; } u;
  unsigned long long* a = (unsigned long long*)p;
  u.q[0] = __hip_atomic_load(a,     __ATOMIC_RELAXED, __HIP_MEMORY_SCOPE_AGENT);
  u.q[1] = __hip_atomic_load(a + 1, __ATOMIC_RELAXED, __HIP_MEMORY_SCOPE_AGENT);
  return u.s;
}

// Arrival with NO cache maintenance: our cross-block data was stored with
// agent-scope (L2-bypassing) atomic stores by this wave; vmcnt(0) drains them,
// then a relaxed RMW publishes. Last arriver bumps gen.
__device__ __forceinline__ void bar_arrive(unsigned int* cnt, unsigned int* gen) {
  asm volatile("s_waitcnt vmcnt(0)" ::: "memory");
  unsigned int old = __hip_atomic_fetch_add(cnt, 1u, __ATOMIC_RELAXED, __HIP_MEMORY_SCOPE_AGENT);
  if (((old + 1) & (NBLK - 1)) == 0u)
    __hip_atomic_store(gen, (old + 1) / NBLK, __ATOMIC_RELAXED, __HIP_MEMORY_SCOPE_AGENT);
}

__global__ void cvt_kernel(const float* __restrict__ src, unsigned short* __restrict__ dst, int n4) {
  int i = blockIdx.x * blockDim.x + threadIdx.x;
  int stride = gridDim.x * blockDim.x;
  for (; i < n4; i += stride) {
    f32x4 v = ((const f32x4*)src)[i];
    union { unsigned short u[4]; unsigned long long q; } o;
    o.u[0] = f2bf(v[0]); o.u[1] = f2bf(v[1]); o.u[2] = f2bf(v[2]); o.u[3] = f2bf(v[3]);
    ((unsigned long long*)dst)[i] = o.q;
  }
}

// Persistent bidirectional LSTM layer scan.
// Grid: 64 blocks x 256 threads. Blocks 0..31 forward, 32..63 backward.
// Each block owns 16 hidden units (64 gate rows). h exchanged via ws ping-pong
// (bf16) through the coherent point; c stays in registers.
// h slot layout: [block jb][batch b][16 units]  (1024 shorts per block slice)
template<int DIN>
__global__ __launch_bounds__(256, 1)
void scan_kernel(const unsigned short* __restrict__ act_in,
                 unsigned short* __restrict__ act_out,
                 const unsigned short* __restrict__ wih_f,
                 const unsigned short* __restrict__ whh_f,
                 const float* __restrict__ bias_f,
                 const unsigned short* __restrict__ wih_b,
                 const unsigned short* __restrict__ whh_b,
                 const float* __restrict__ bias_b,
                 const float* __restrict__ init_f,
                 const float* __restrict__ init_b,
                 const float* __restrict__ masks,
                 unsigned short* hb,          // [2 dirs][2 slots][HSLOT] bf16
                 unsigned int* bar,           // per layer: [dir][{cnt@0, gen@16}] uints, 64B apart
                 float* out_h, float* out_c)
{
  const int bid  = blockIdx.x;
  const int dir  = bid >> 5;
  const int jb   = bid & (NBLK - 1);
  const int j0   = jb * UB;
  const int lane = threadIdx.x & 63;
  const int wave = threadIdx.x >> 6;
  const int n    = lane & 15;
  const int kb   = lane >> 4;
  const int u    = n & 7;
  const bool hif = (n >= 8);

  const unsigned short* wih = dir ? wih_b : wih_f;
  const unsigned short* whh = dir ? whh_b : whh_f;
  const float* bias = dir ? bias_b : bias_f;
  const float* init = dir ? init_b : init_f;
  unsigned int* cnt = bar + dir * 32;
  unsigned int* gen = cnt + 16;
  unsigned short* hbd = hb + dir * (2 * HSLOT);
  float* oh = out_h + dir * (NBATCH * HID);
  float* oc = out_c + dir * (NBATCH * HID);

  // gate-row index per 16-wide n-tile. tiles: 0=[i|f] u0-7, 1=[i|f] u8-15,
  // 2=[g|o] u0-7, 3=[g|o] u8-15
  int wr[4];
  wr[0] = hif ? (512 + j0 + u) : (j0 + u);
  wr[1] = wr[0] + 8;
  wr[2] = wr[0] + 1024;
  wr[3] = wr[0] + 1032;

  float bb[4];
  const unsigned short* wihp[4];
  const unsigned short* whhp[4];
  #pragma unroll
  for (int q = 0; q < 4; ++q) {
    bb[q] = bias[wr[q]];
    wihp[q] = wih + wr[q] * DIN + kb * 8;
    whhp[q] = whh + wr[q] * HID + kb * 8;
  }

  __shared__ unsigned short lsm[NBATCH * UB];  // 2KB pack buffer

  // h0 init into slot 0 (this block's 64x16 slice), via agent-scope stores
  if (wave == 0) {
    union { unsigned short us[16]; unsigned long long q[4]; } iv;
    #pragma unroll
    for (int k = 0; k < 16; ++k) iv.us[k] = f2bf(init[j0 + k]);
    unsigned long long* hd = (unsigned long long*)(hbd + jb * (NBATCH * UB) + lane * UB);
    #pragma unroll
    for (int k = 0; k < 4; ++k)
      __hip_atomic_store(hd + k, iv.q[k], __ATOMIC_RELAXED, __HIP_MEMORY_SCOPE_AGENT);
  }
  float cs[2][4];
  #pragma unroll
  for (int uh = 0; uh < 2; ++uh)
    #pragma unroll
    for (int i = 0; i < 4; ++i)
      cs[uh][i] = init[512 + j0 + uh * 8 + u];

  if (threadIdx.x == 0) bar_arrive(cnt, gen);

  f32x4 acc_e[4], acc_o[4];

  auto wih_load = [&](int tstep) {
    #pragma unroll
    for (int q = 0; q < 4; ++q) {
      acc_e[q] = (f32x4){bb[q], bb[q], bb[q], bb[q]};
      acc_o[q] = (f32x4){0.f, 0.f, 0.f, 0.f};
    }
    const int tt2 = dir ? (TSTEPS - 1 - tstep) : tstep;
    const unsigned short* arow = act_in + ((size_t)tt2 * NBATCH + wave * 16 + n) * DIN + kb * 8;
    #pragma unroll
    for (int kt = 0; kt < DIN / 32; kt += 2) {
      short8 a0 = *(const short8*)(arow + kt * 32);
      short8 a1 = *(const short8*)(arow + kt * 32 + 32);
      #pragma unroll
      for (int q = 0; q < 4; ++q) {
        acc_e[q] = MFMA_B16(a0, *(const short8*)(wihp[q] + kt * 32), acc_e[q]);
        acc_o[q] = MFMA_B16(a1, *(const short8*)(wihp[q] + kt * 32 + 32), acc_o[q]);
      }
    }
  };

  wih_load(0);

  for (int t = 0; t < TSTEPS; ++t) {
    if (threadIdx.x == 0) {
      while (__hip_atomic_load(gen, __ATOMIC_RELAXED, __HIP_MEMORY_SCOPE_AGENT) < (unsigned int)(t + 1))
        __builtin_amdgcn_s_sleep(2);
    }
    __syncthreads();

    // recurrent part: h(t-1) @ Whh_slice, h read from coherent point
    {
      const unsigned short* hcur = hbd + (t & 1) * HSLOT;
      const unsigned short* hrow = hcur + (kb >> 1) * 1024 + (kb & 1) * 8 + (wave * 16 + n) * UB;
      #pragma unroll
      for (int kt = 0; kt < 16; kt += 2) {
        short8 a0 = ld_llc16(hrow + kt * 2048);
        short8 a1 = ld_llc16(hrow + kt * 2048 + 2048);
        #pragma unroll
        for (int q = 0; q < 4; ++q) {
          acc_e[q] = MFMA_B16(a0, *(const short8*)(whhp[q] + kt * 32), acc_e[q]);
          acc_o[q] = MFMA_B16(a1, *(const short8*)(whhp[q] + kt * 32 + 32), acc_o[q]);
        }
      }
    }

    const int tt = dir ? (TSTEPS - 1 - t) : t;
    f32x4 mk = *(const f32x4*)(masks + tt * NBATCH + wave * 16 + kb * 4);

    #pragma unroll
    for (int uh = 0; uh < 2; ++uh) {
      f32x4 aif = acc_e[uh] + acc_o[uh];
      f32x4 ago = acc_e[2 + uh] + acc_o[2 + uh];
      f32x4 oif, ogo;
      #pragma unroll
      for (int r = 0; r < 4; ++r) {
        oif[r] = __shfl_xor(aif[r], 8, 64);
        ogo[r] = __shfl_xor(ago[r], 8, 64);
      }
      #pragma unroll
      for (int i = 0; i < 4; ++i) {
        float vi = hif ? oif[i] : aif[i];
        float vf = hif ? aif[i] : oif[i];
        float vg = hif ? ogo[i] : ago[i];
        float vo = hif ? ago[i] : ogo[i];
        float cn = (sigm(vf) * cs[uh][i] + sigm(vi) * tanhf_(vg)) * mk[i];
        float hvv = sigm(vo) * tanhf_(cn) * mk[i];
        cs[uh][i] = cn;
        if (!hif) {
          const int b = wave * 16 + kb * 4 + i;
          lsm[b * UB + uh * 8 + u] = f2bf(hvv);
          if (t == TSTEPS - 1) {
            oh[b * HID + j0 + uh * 8 + u] = hvv;
            oc[b * HID + j0 + uh * 8 + u] = cn;
          }
        }
      }
    }

    __syncthreads();  // drains all waves' LDS writes

    // wave 0 flushes the block's 2KB h-slice: agent-scope stores to h slot,
    // plus coalesced act_out stores. lane == batch.
    if (wave == 0) {
      const unsigned long long* lq = (const unsigned long long*)lsm;
      unsigned long long q0 = lq[lane * 4 + 0];
      unsigned long long q1 = lq[lane * 4 + 1];
      unsigned long long q2 = lq[lane * 4 + 2];
      unsigned long long q3 = lq[lane * 4 + 3];
      unsigned short* hnxt = hbd + ((t + 1) & 1) * HSLOT;
      unsigned long long* hd = (unsigned long long*)(hnxt + jb * (NBATCH * UB) + lane * UB);
      __hip_atomic_store(hd + 0, q0, __ATOMIC_RELAXED, __HIP_MEMORY_SCOPE_AGENT);
      __hip_atomic_store(hd + 1, q1, __ATOMIC_RELAXED, __HIP_MEMORY_SCOPE_AGENT);
      __hip_atomic_store(hd + 2, q2, __ATOMIC_RELAXED, __HIP_MEMORY_SCOPE_AGENT);
      __hip_atomic_store(hd + 3, q3, __ATOMIC_RELAXED, __HIP_MEMORY_SCOPE_AGENT);
      union { unsigned long long q[2]; short8 s; } p0, p1;
      p0.q[0] = q0; p0.q[1] = q1; p1.q[0] = q2; p1.q[1] = q3;
      short8* ar = (short8*)(act_out + ((size_t)tt * NBATCH + lane) * (2 * HID) + dir * HID + j0);
      ar[0] = p0.s;
      ar[1] = p1.s;
    }
    if (threadIdx.x == 0) bar_arrive(cnt, gen);

    // overlap: input-projection for t+1 while other blocks finish their step
    if (t + 1 < TSTEPS) wih_load(t + 1);
  }
}

// Highway gate: g = sigmoid(raw @ projW^T + projb); out = g*raw + (1-g)*inp
// FINAL=0: write bf16 in-place over inp. FINAL=1: write fp32 to outf.
template<int FINAL>
__global__ __launch_bounds__(256)
void highway_kernel(const unsigned short* __restrict__ raw,
                    unsigned short* __restrict__ inp,
                    const unsigned short* __restrict__ pw,
                    const float* __restrict__ pb,
                    float* __restrict__ outf)
{
  const int lane = threadIdx.x & 63;
  const int wave = threadIdx.x >> 6;
  const int n = lane & 15, kb = lane >> 4;
  const int r0 = blockIdx.x * 64 + wave * 16;
  const int c0 = blockIdx.y * 64;

  f32x4 acc[4];
  #pragma unroll
  for (int nt = 0; nt < 4; ++nt) {
    float b = pb[c0 + nt * 16 + n];
    acc[nt] = (f32x4){b, b, b, b};
  }
  const unsigned short* arow = raw + (r0 + n) * 1024 + kb * 8;
  #pragma unroll 4
  for (int kt = 0; kt < 32; ++kt) {
    short8 a = *(const short8*)(arow + kt * 32);
    #pragma unroll
    for (int nt = 0; nt < 4; ++nt) {
      short8 b = *(const short8*)(pw + (c0 + nt * 16 + n) * 1024 + kt * 32 + kb * 8);
      acc[nt] = MFMA_B16(a, b, acc[nt]);
    }
  }
  #pragma unroll
  for (int nt = 0; nt < 4; ++nt) {
    #pragma unroll
    for (int i = 0; i < 4; ++i) {
      int row = r0 + kb * 4 + i;
      int col = c0 + nt * 16 + n;
      float g = sigm(acc[nt][i]);
      float rv = bf2f(raw[row * 1024 + col]);
      float iv = bf2f(inp[row * 1024 + col]);
      float ov = g * rv + (1.0f - g) * iv;
      if (FINAL) outf[row * 1024 + col] = ov;
      else       inp[row * 1024 + col] = f2bf(ov);
    }
  }
}

extern "C" void kernel_launch(void* const* d_in, const int* in_sizes, int n_in,
                              void* d_out, int out_size, void* d_ws, size_t ws_size,
                              hipStream_t stream) {
  const float* x     = (const float*)d_in[0];
  const float* masks = (const float*)d_in[1];
  const float* fWih0 = (const float*)d_in[2];
  const float* fWihR = (const float*)d_in[3];
  const float* fWhh  = (const float*)d_in[4];
  const float* fb    = (const float*)d_in[5];
  const float* bWih0 = (const float*)d_in[6];
  const float* bWihR = (const float*)d_in[7];
  const float* bWhh  = (const float*)d_in[8];
  const float* bbias = (const float*)d_in[9];
  const float* fInit = (const float*)d_in[10];
  const float* bInit = (const float*)d_in[11];
  const float* projW = (const float*)d_in[12];
  const float* projB = (const float*)d_in[13];
  float* out = (float*)d_out;

  char* ws = (char*)d_ws;
  unsigned short* bufA = (unsigned short*)(ws + 0);           // 33,554,432 B
  unsigned short* bufB = (unsigned short*)(ws + 33554432);    // 33,554,432 B
  unsigned short* xbf  = (unsigned short*)(ws + 67108864);    // 16,777,216 B
  unsigned short* wf0  = (unsigned short*)(ws + 83886080);    //  2,097,152 B
  unsigned short* wf12 = (unsigned short*)(ws + 85983232);    //  8,388,608 B
  unsigned short* whf  = (unsigned short*)(ws + 94371840);    //  6,291,456 B
  unsigned short* wb0  = (unsigned short*)(ws + 100663296);   //  2,097,152 B
  unsigned short* wb12 = (unsigned short*)(ws + 102760448);   //  8,388,608 B
  unsigned short* whb  = (unsigned short*)(ws + 111149056);   //  6,291,456 B
  unsigned short* pj   = (unsigned short*)(ws + 117440512);   //  4,194,304 B
  unsigned short* hbuf = (unsigned short*)(ws + 121634816);   //    262,144 B
  unsigned int*   bar  = (unsigned int*)(ws + 121896960);     //        768 B

  hipMemsetAsync(bar, 0, 768, stream);

  cvt_kernel<<<1024, 256, 0, stream>>>(x,     xbf,  (256*64*512)   / 4);
  cvt_kernel<<<1024, 256, 0, stream>>>(fWih0, wf0,  (2048*512)     / 4);
  cvt_kernel<<<1024, 256, 0, stream>>>(fWihR, wf12, (2*2048*1024)  / 4);
  cvt_kernel<<<1024, 256, 0, stream>>>(fWhh,  whf,  (3*2048*512)   / 4);
  cvt_kernel<<<1024, 256, 0, stream>>>(bWih0, wb0,  (2048*512)     / 4);
  cvt_kernel<<<1024, 256, 0, stream>>>(bWihR, wb12, (2*2048*1024)  / 4);
  cvt_kernel<<<1024, 256, 0, stream>>>(bWhh,  whb,  (3*2048*512)   / 4);
  cvt_kernel<<<1024, 256, 0, stream>>>(projW, pj,   (2*1024*1024)  / 4);

  float* outH = out + 16777216;
  float* outC = out + 16777216 + 6*64*512;

  // layer 0
  scan_kernel<512><<<64, 256, 0, stream>>>(
      xbf, bufA,
      wf0, whf, fb,
      wb0, whb, bbias,
      fInit, bInit,
      masks, hbuf, bar,
      outH, outC);
  // layer 1
  scan_kernel<1024><<<64, 256, 0, stream>>>(
      bufA, bufB,
      wf12,               whf + 2048*512,   fb + 2048,
      wb12,               whb + 2048*512,   bbias + 2048,
      fInit + 1024, bInit + 1024,
      masks, hbuf, bar + 64,
      outH + 2*64*512, outC + 2*64*512);
  highway_kernel<0><<<dim3(256, 16), 256, 0, stream>>>(bufB, bufA, pj, projB, nullptr);
  // layer 2
  scan_kernel<1024><<<64, 256, 0, stream>>>(
      bufA, bufB,
      wf12 + 2048*1024,   whf + 2*2048*512, fb + 2*2048,
      wb12 + 2048*1024,   whb + 2*2048*512, bbias + 2*2048,
      fInit + 2048, bInit + 2048,
      masks, hbuf, bar + 128,
      outH + 4*64*512, outC + 4*64*512);
  highway_kernel<1><<<dim3(256, 16), 256, 0, stream>>>(bufB, bufA, pj + 1024*1024, projB + 1024, out);
}

// Round 3
// 6505.151 us; speedup vs baseline: 3.0479x; 3.0479x over previous
//
#include <hip/hip_runtime.h>

typedef __attribute__((ext_vector_type(8))) short short8;
typedef __attribute__((ext_vector_type(4))) float f32x4;

#define MFMA_B16(a, b, c) __builtin_amdgcn_mfma_f32_16x16x32_bf16((a), (b), (c), 0, 0, 0)

#define TSTEPS 256
#define NBATCH 64
#define HID    512
#define NBLK   32   // blocks per direction
#define UB     16   // hidden units per block
#define HSLOT  (NBATCH * HID)  // shorts per h slot per dir

__device__ __forceinline__ unsigned short f2bf(float f) {
  unsigned int u = __float_as_uint(f);
  u += 0x7fffu + ((u >> 16) & 1u);
  return (unsigned short)(u >> 16);
}
__device__ __forceinline__ float bf2f(unsigned short s) {
  return __uint_as_float(((unsigned int)s) << 16);
}
__device__ __forceinline__ float sigm(float x) { return 1.0f / (1.0f + __expf(-x)); }
__device__ __forceinline__ float tanhf_(float x) {
  float xc = fminf(fmaxf(x, -15.0f), 15.0f);
  float e = __expf(2.0f * xc);
  return (e - 1.0f) / (e + 1.0f);
}

// 16B load from the coherent point (bypasses stale L1/L2), relaxed
__device__ __forceinline__ short8 ld_llc16(const unsigned short* p) {
  union { unsigned long long q[2]; short8 s; } u;
  unsigned long long* a = (unsigned long long*)p;
  u.q[0] = __hip_atomic_load(a,     __ATOMIC_RELAXED, __HIP_MEMORY_SCOPE_AGENT);
  u.q[1] = __hip_atomic_load(a + 1, __ATOMIC_RELAXED, __HIP_MEMORY_SCOPE_AGENT);
  return u.s;
}

// Arrival with no cache maintenance: cross-block data was stored with
// agent-scope (L2-bypassing) atomic stores by this wave; vmcnt(0) drains them,
// then a relaxed RMW publishes. Last arriver bumps gen.
__device__ __forceinline__ void bar_arrive(unsigned int* cnt, unsigned int* gen) {
  asm volatile("s_waitcnt vmcnt(0)" ::: "memory");
  unsigned int old = __hip_atomic_fetch_add(cnt, 1u, __ATOMIC_RELAXED, __HIP_MEMORY_SCOPE_AGENT);
  if (((old + 1) & (NBLK - 1)) == 0u)
    __hip_atomic_store(gen, (old + 1) / NBLK, __ATOMIC_RELAXED, __HIP_MEMORY_SCOPE_AGENT);
}

__global__ void cvt_kernel(const float* __restrict__ src, unsigned short* __restrict__ dst, int n4) {
  int i = blockIdx.x * blockDim.x + threadIdx.x;
  int stride = gridDim.x * blockDim.x;
  for (; i < n4; i += stride) {
    f32x4 v = ((const f32x4*)src)[i];
    union { unsigned short u[4]; unsigned long long q; } o;
    o.u[0] = f2bf(v[0]); o.u[1] = f2bf(v[1]); o.u[2] = f2bf(v[2]); o.u[3] = f2bf(v[3]);
    ((unsigned long long*)dst)[i] = o.q;
  }
}

// gates_x precompute: gates[t][r][b] = sum_k wcat[r][k]*act[t*64+b][k] + bias(r)
// wcat rows 0..2047 = forward dir, 2048..4095 = backward dir (bias likewise).
// Grid: (16 row-blocks, 256 t), 256 threads. Wave w: rows [w*64, w*64+64).
template<int K>
__global__ __launch_bounds__(256)
void gates_gemm(const unsigned short* __restrict__ act,
                const unsigned short* __restrict__ wcat,
                const float* __restrict__ bias_f,
                const float* __restrict__ bias_b,
                unsigned short* __restrict__ gates)
{
  const int lane = threadIdx.x & 63;
  const int wave = threadIdx.x >> 6;
  const int n = lane & 15, kb = lane >> 4;
  const int t = blockIdx.y;
  const int rbase = blockIdx.x * 256 + wave * 64;

  f32x4 acc[4][4];
  #pragma unroll
  for (int mt = 0; mt < 4; ++mt) {
    f32x4 bi;
    #pragma unroll
    for (int i = 0; i < 4; ++i) {
      int r = rbase + mt * 16 + kb * 4 + i;
      bi[i] = (r < 2048) ? bias_f[r] : bias_b[r - 2048];
    }
    #pragma unroll
    for (int nt = 0; nt < 4; ++nt) acc[mt][nt] = bi;
  }

  const unsigned short* wrow = wcat + (size_t)(rbase + n) * K + kb * 8;
  const unsigned short* arow = act + ((size_t)t * 64 + n) * K + kb * 8;
  #pragma unroll 4
  for (int ks = 0; ks < K / 32; ++ks) {
    short8 af[4], bf_[4];
    #pragma unroll
    for (int mt = 0; mt < 4; ++mt) af[mt] = *(const short8*)(wrow + (size_t)mt * 16 * K + ks * 32);
    #pragma unroll
    for (int nt = 0; nt < 4; ++nt) bf_[nt] = *(const short8*)(arow + (size_t)nt * 16 * K + ks * 32);
    #pragma unroll
    for (int mt = 0; mt < 4; ++mt)
      #pragma unroll
      for (int nt = 0; nt < 4; ++nt)
        acc[mt][nt] = MFMA_B16(af[mt], bf_[nt], acc[mt][nt]);
  }

  unsigned short* gbase = gates + (size_t)t * 4096 * 64;
  #pragma unroll
  for (int mt = 0; mt < 4; ++mt)
    #pragma unroll
    for (int i = 0; i < 4; ++i) {
      int r = rbase + mt * 16 + kb * 4 + i;
      #pragma unroll
      for (int nt = 0; nt < 4; ++nt)
        gbase[(size_t)r * 64 + nt * 16 + n] = f2bf(acc[mt][nt][i]);
    }
}

// Persistent bidirectional LSTM layer scan.
// Grid: 64 blocks x 256 threads. Blocks 0..31 forward, 32..63 backward.
// Each block owns 16 hidden units (64 gate rows). Whh slice staged in LDS in
// exact MFMA B-fragment order (conflict-free ds_read_b128, zero per-step
// weight traffic). h exchanged via ws ping-pong through the coherent point;
// c stays in registers.
// GXP=1: gate pre-activations (incl. bias) read from precomputed gates buffer.
// GXP=0: fallback, computes x@Wih^T in-scan (round-2 style).
template<int DIN, int GXP>
__global__ __launch_bounds__(256, 1)
void scan_kernel(const unsigned short* __restrict__ act_in,
                 const unsigned short* __restrict__ gates,   // [T][4096][64] bf16
                 unsigned short* __restrict__ act_out,
                 const unsigned short* __restrict__ wih_f,
                 const unsigned short* __restrict__ wih_b,
                 const unsigned short* __restrict__ whh_f,
                 const unsigned short* __restrict__ whh_b,
                 const float* __restrict__ bias_f,
                 const float* __restrict__ bias_b,
                 const float* __restrict__ init_f,
                 const float* __restrict__ init_b,
                 const float* __restrict__ masks,
                 unsigned short* hb,          // [2 dirs][2 slots][HSLOT] bf16
                 unsigned int* bar,           // per layer: dir d: cnt@d*128, gen@d*128+64
                 float* out_h, float* out_c)
{
  const int bid  = blockIdx.x;
  const int dir  = bid >> 5;
  const int jb   = bid & (NBLK - 1);
  const int j0   = jb * UB;
  const int lane = threadIdx.x & 63;
  const int wave = threadIdx.x >> 6;
  const int n    = lane & 15;
  const int kb   = lane >> 4;
  const int u    = n & 7;
  const bool hif = (n >= 8);

  const unsigned short* wih = dir ? wih_b : wih_f;
  const unsigned short* whh = dir ? whh_b : whh_f;
  const float* bias = dir ? bias_b : bias_f;
  const float* init = dir ? init_b : init_f;
  unsigned int* cnt = bar + dir * 128;
  unsigned int* gen = cnt + 64;
  unsigned short* hbd = hb + dir * (2 * HSLOT);
  float* oh = out_h + dir * (NBATCH * HID);
  float* oc = out_c + dir * (NBATCH * HID);

  // gate-row index per 16-wide n-tile. tiles: 0=[i|f] u0-7, 1=[i|f] u8-15,
  // 2=[g|o] u0-7, 3=[g|o] u8-15
  int wr[4];
  wr[0] = hif ? (512 + j0 + u) : (j0 + u);
  wr[1] = wr[0] + 8;
  wr[2] = wr[0] + 1024;
  wr[3] = wr[0] + 1032;

  float bb[4];
  const unsigned short* wihp[4];
  #pragma unroll
  for (int q = 0; q < 4; ++q) {
    bb[q] = bias[wr[q]];
    wihp[q] = wih + (size_t)wr[q] * DIN + kb * 8;
  }

  // Whh in LDS, pre-swizzled to per-lane fragment order:
  // wlds[(ks*4+q)*64 + lane] = Whh[growS(q, lane&15)][ks*32 + (lane>>4)*8 ..+7]
  __shared__ short8 wlds[16 * 4 * 64];             // 64 KB
  __shared__ unsigned short lsm[NBATCH * UB];      // 2 KB pack buffer

  for (int g = threadIdx.x; g < 4096; g += 256) {
    int n_ = g & 15, kb_ = (g >> 4) & 3, q_ = (g >> 6) & 3, ks_ = g >> 8;
    int grow = ((n_ >= 8) ? 512 : 0) + j0 + (n_ & 7) + (q_ & 1) * 8 + (q_ >> 1) * 1024;
    wlds[g] = *(const short8*)(whh + (size_t)grow * HID + ks_ * 32 + kb_ * 8);
  }

  // h0 init into slot 0 (this block's 64x16 slice), via agent-scope stores
  if (wave == 0) {
    union { unsigned short us[16]; unsigned long long q[4]; } iv;
    #pragma unroll
    for (int k = 0; k < 16; ++k) iv.us[k] = f2bf(init[j0 + k]);
    unsigned long long* hd = (unsigned long long*)(hbd + jb * (NBATCH * UB) + lane * UB);
    #pragma unroll
    for (int k = 0; k < 4; ++k)
      __hip_atomic_store(hd + k, iv.q[k], __ATOMIC_RELAXED, __HIP_MEMORY_SCOPE_AGENT);
  }
  float cs[2][4];
  #pragma unroll
  for (int uh = 0; uh < 2; ++uh)
    #pragma unroll
    for (int i = 0; i < 4; ++i)
      cs[uh][i] = init[512 + j0 + uh * 8 + u];

  __syncthreads();  // LDS staging + h0 done
  if (threadIdx.x == 0) bar_arrive(cnt, gen);

  f32x4 acc_e[4], acc_o[4];

  auto wih_load = [&](int tstep) {
    #pragma unroll
    for (int q = 0; q < 4; ++q) {
      acc_e[q] = (f32x4){bb[q], bb[q], bb[q], bb[q]};
      acc_o[q] = (f32x4){0.f, 0.f, 0.f, 0.f};
    }
    const int tt2 = dir ? (TSTEPS - 1 - tstep) : tstep;
    const unsigned short* arow = act_in + ((size_t)tt2 * NBATCH + wave * 16 + n) * DIN + kb * 8;
    #pragma unroll
    for (int kt = 0; kt < DIN / 32; kt += 2) {
      short8 a0 = *(const short8*)(arow + kt * 32);
      short8 a1 = *(const short8*)(arow + kt * 32 + 32);
      #pragma unroll
      for (int q = 0; q < 4; ++q) {
        acc_e[q] = MFMA_B16(a0, *(const short8*)(wihp[q] + kt * 32), acc_e[q]);
        acc_o[q] = MFMA_B16(a1, *(const short8*)(wihp[q] + kt * 32 + 32), acc_o[q]);
      }
    }
  };

  if (!GXP) wih_load(0);

  for (int t = 0; t < TSTEPS; ++t) {
    const int tt = dir ? (TSTEPS - 1 - t) : t;

    if (GXP) {
      // gate pre-activations (incl. bias): issued before the poll, completes
      // in its shadow
      const unsigned short* gb = gates + ((size_t)tt * 4096 + dir * 2048) * 64 + wave * 16 + kb * 4;
      #pragma unroll
      for (int q = 0; q < 4; ++q) {
        union { unsigned long long q8; unsigned short us[4]; } gv;
        gv.q8 = *(const unsigned long long*)(gb + (size_t)wr[q] * 64);
        acc_e[q] = (f32x4){bf2f(gv.us[0]), bf2f(gv.us[1]), bf2f(gv.us[2]), bf2f(gv.us[3])};
        acc_o[q] = (f32x4){0.f, 0.f, 0.f, 0.f};
      }
    }

    if (threadIdx.x == 0) {
      while (__hip_atomic_load(gen, __ATOMIC_RELAXED, __HIP_MEMORY_SCOPE_AGENT) < (unsigned int)(t + 1))
        __builtin_amdgcn_s_sleep(1);
    }
    __syncthreads();

    // recurrent part: h(t-1) @ Whh_slice; h from coherent point, Whh from LDS
    {
      const unsigned short* hrow = hbd + (t & 1) * HSLOT
                                 + (kb >> 1) * 1024 + (kb & 1) * 8 + (wave * 16 + n) * UB;
      short8 hf[16];
      #pragma unroll
      for (int ks = 0; ks < 16; ++ks) hf[ks] = ld_llc16(hrow + ks * 2048);
      #pragma unroll
      for (int ks = 0; ks < 16; ++ks) {
        f32x4* ac = (ks & 1) ? acc_o : acc_e;
        #pragma unroll
        for (int q = 0; q < 4; ++q)
          ac[q] = MFMA_B16(hf[ks], wlds[(ks * 4 + q) * 64 + lane], ac[q]);
      }
    }

    f32x4 mk = *(const f32x4*)(masks + tt * NBATCH + wave * 16 + kb * 4);

    #pragma unroll
    for (int uh = 0; uh < 2; ++uh) {
      f32x4 aif = acc_e[uh] + acc_o[uh];
      f32x4 ago = acc_e[2 + uh] + acc_o[2 + uh];
      f32x4 oif, ogo;
      #pragma unroll
      for (int r = 0; r < 4; ++r) {
        oif[r] = __shfl_xor(aif[r], 8, 64);
        ogo[r] = __shfl_xor(ago[r], 8, 64);
      }
      #pragma unroll
      for (int i = 0; i < 4; ++i) {
        float vi = hif ? oif[i] : aif[i];
        float vf = hif ? aif[i] : oif[i];
        float vg = hif ? ogo[i] : ago[i];
        float vo = hif ? ago[i] : ogo[i];
        float cn = (sigm(vf) * cs[uh][i] + sigm(vi) * tanhf_(vg)) * mk[i];
        float hvv = sigm(vo) * tanhf_(cn) * mk[i];
        cs[uh][i] = cn;
        if (!hif) {
          const int b = wave * 16 + kb * 4 + i;
          lsm[b * UB + uh * 8 + u] = f2bf(hvv);
          if (t == TSTEPS - 1) {
            oh[b * HID + j0 + uh * 8 + u] = hvv;
            oc[b * HID + j0 + uh * 8 + u] = cn;
          }
        }
      }
    }

    __syncthreads();  // drains all waves' LDS writes

    // wave 0 flushes the block's 2KB h-slice: agent-scope stores to h slot,
    // plus coalesced act_out stores. lane == batch.
    if (wave == 0) {
      const unsigned long long* lq = (const unsigned long long*)lsm;
      unsigned long long q0 = lq[lane * 4 + 0];
      unsigned long long q1 = lq[lane * 4 + 1];
      unsigned long long q2 = lq[lane * 4 + 2];
      unsigned long long q3 = lq[lane * 4 + 3];
      unsigned short* hnxt = hbd + ((t + 1) & 1) * HSLOT;
      unsigned long long* hd = (unsigned long long*)(hnxt + jb * (NBATCH * UB) + lane * UB);
      __hip_atomic_store(hd + 0, q0, __ATOMIC_RELAXED, __HIP_MEMORY_SCOPE_AGENT);
      __hip_atomic_store(hd + 1, q1, __ATOMIC_RELAXED, __HIP_MEMORY_SCOPE_AGENT);
      __hip_atomic_store(hd + 2, q2, __ATOMIC_RELAXED, __HIP_MEMORY_SCOPE_AGENT);
      __hip_atomic_store(hd + 3, q3, __ATOMIC_RELAXED, __HIP_MEMORY_SCOPE_AGENT);
      union { unsigned long long q[2]; short8 s; } p0, p1;
      p0.q[0] = q0; p0.q[1] = q1; p1.q[0] = q2; p1.q[1] = q3;
      short8* ar = (short8*)(act_out + ((size_t)tt * NBATCH + lane) * (2 * HID) + dir * HID + j0);
      ar[0] = p0.s;
      ar[1] = p1.s;
    }
    if (threadIdx.x == 0) bar_arrive(cnt, gen);

    if (!GXP && t + 1 < TSTEPS) wih_load(t + 1);
  }
}

// Highway gate: g = sigmoid(raw @ projW^T + projb); out = g*raw + (1-g)*inp
// FINAL=0: write bf16 in-place over inp. FINAL=1: write fp32 to outf.
template<int FINAL>
__global__ __launch_bounds__(256)
void highway_kernel(const unsigned short* __restrict__ raw,
                    unsigned short* __restrict__ inp,
                    const unsigned short* __restrict__ pw,
                    const float* __restrict__ pb,
                    float* __restrict__ outf)
{
  const int lane = threadIdx.x & 63;
  const int wave = threadIdx.x >> 6;
  const int n = lane & 15, kb = lane >> 4;
  const int r0 = blockIdx.x * 64 + wave * 16;
  const int c0 = blockIdx.y * 64;

  f32x4 acc[4];
  #pragma unroll
  for (int nt = 0; nt < 4; ++nt) {
    float b = pb[c0 + nt * 16 + n];
    acc[nt] = (f32x4){b, b, b, b};
  }
  const unsigned short* arow = raw + (r0 + n) * 1024 + kb * 8;
  #pragma unroll 4
  for (int kt = 0; kt < 32; ++kt) {
    short8 a = *(const short8*)(arow + kt * 32);
    #pragma unroll
    for (int nt = 0; nt < 4; ++nt) {
      short8 b = *(const short8*)(pw + (c0 + nt * 16 + n) * 1024 + kt * 32 + kb * 8);
      acc[nt] = MFMA_B16(a, b, acc[nt]);
    }
  }
  #pragma unroll
  for (int nt = 0; nt < 4; ++nt) {
    #pragma unroll
    for (int i = 0; i < 4; ++i) {
      int row = r0 + kb * 4 + i;
      int col = c0 + nt * 16 + n;
      float g = sigm(acc[nt][i]);
      float rv = bf2f(raw[row * 1024 + col]);
      float iv = bf2f(inp[row * 1024 + col]);
      float ov = g * rv + (1.0f - g) * iv;
      if (FINAL) outf[row * 1024 + col] = ov;
      else       inp[row * 1024 + col] = f2bf(ov);
    }
  }
}

extern "C" void kernel_launch(void* const* d_in, const int* in_sizes, int n_in,
                              void* d_out, int out_size, void* d_ws, size_t ws_size,
                              hipStream_t stream) {
  const float* x     = (const float*)d_in[0];
  const float* masks = (const float*)d_in[1];
  const float* fWih0 = (const float*)d_in[2];
  const float* fWihR = (const float*)d_in[3];
  const float* fWhh  = (const float*)d_in[4];
  const float* fb    = (const float*)d_in[5];
  const float* bWih0 = (const float*)d_in[6];
  const float* bWihR = (const float*)d_in[7];
  const float* bWhh  = (const float*)d_in[8];
  const float* bbias = (const float*)d_in[9];
  const float* fInit = (const float*)d_in[10];
  const float* bInit = (const float*)d_in[11];
  const float* projW = (const float*)d_in[12];
  const float* projB = (const float*)d_in[13];
  float* out = (float*)d_out;

  char* ws = (char*)d_ws;
  unsigned short* bufA  = (unsigned short*)(ws + 0);           // 33,554,432
  unsigned short* bufB  = (unsigned short*)(ws + 33554432);    // 33,554,432
  unsigned short* xbf   = (unsigned short*)(ws + 67108864);    // 16,777,216
  unsigned short* wcat0 = (unsigned short*)(ws + 83886080);    //  4,194,304 [4096][512]
  unsigned short* wcat1 = (unsigned short*)(ws + 88080384);    //  8,388,608 [4096][1024]
  unsigned short* wcat2 = (unsigned short*)(ws + 96468992);    //  8,388,608
  unsigned short* whf   = (unsigned short*)(ws + 104857600);   //  6,291,456
  unsigned short* whb   = (unsigned short*)(ws + 111149056);   //  6,291,456
  unsigned short* pj    = (unsigned short*)(ws + 117440512);   //  4,194,304
  unsigned short* hbuf  = (unsigned short*)(ws + 121634816);   //    262,144
  unsigned int*   bar   = (unsigned int*)(ws + 121896960);     //      4,096
  unsigned short* gates = (unsigned short*)(ws + 121901056);   // 134,217,728 [256][4096][64]
  const bool gx = ws_size >= 256118784ull;

  hipMemsetAsync(bar, 0, 4096, stream);

  cvt_kernel<<<1024, 256, 0, stream>>>(x,     xbf,   (256*64*512)  / 4);
  cvt_kernel<<<1024, 256, 0, stream>>>(fWih0, wcat0,              (2048*512)  / 4);
  cvt_kernel<<<1024, 256, 0, stream>>>(bWih0, wcat0 + 2048*512,   (2048*512)  / 4);
  cvt_kernel<<<1024, 256, 0, stream>>>(fWihR,             wcat1,             (2048*1024) / 4);
  cvt_kernel<<<1024, 256, 0, stream>>>(bWihR,             wcat1 + 2048*1024, (2048*1024) / 4);
  cvt_kernel<<<1024, 256, 0, stream>>>(fWihR + 2048*1024, wcat2,             (2048*1024) / 4);
  cvt_kernel<<<1024, 256, 0, stream>>>(bWihR + 2048*1024, wcat2 + 2048*1024, (2048*1024) / 4);
  cvt_kernel<<<1024, 256, 0, stream>>>(fWhh,  whf,   (3*2048*512)  / 4);
  cvt_kernel<<<1024, 256, 0, stream>>>(bWhh,  whb,   (3*2048*512)  / 4);
  cvt_kernel<<<1024, 256, 0, stream>>>(projW, pj,    (2*1024*1024) / 4);

  float* outH = out + 16777216;
  float* outC = out + 16777216 + 6*64*512;

  if (gx) {
    // layer 0
    gates_gemm<512><<<dim3(16, 256), 256, 0, stream>>>(xbf, wcat0, fb, bbias, gates);
    scan_kernel<512, 1><<<64, 256, 0, stream>>>(
        xbf, gates, bufA,
        wcat0, wcat0 + 2048*512, whf, whb,
        fb, bbias, fInit, bInit, masks, hbuf, bar,
        outH, outC);
    // layer 1
    gates_gemm<1024><<<dim3(16, 256), 256, 0, stream>>>(bufA, wcat1, fb + 2048, bbias + 2048, gates);
    scan_kernel<1024, 1><<<64, 256, 0, stream>>>(
        bufA, gates, bufB,
        wcat1, wcat1 + 2048*1024, whf + 2048*512, whb + 2048*512,
        fb + 2048, bbias + 2048, fInit + 1024, bInit + 1024, masks, hbuf, bar + 256,
        outH + 2*64*512, outC + 2*64*512);
    highway_kernel<0><<<dim3(256, 16), 256, 0, stream>>>(bufB, bufA, pj, projB, nullptr);
    // layer 2
    gates_gemm<1024><<<dim3(16, 256), 256, 0, stream>>>(bufA, wcat2, fb + 2*2048, bbias + 2*2048, gates);
    scan_kernel<1024, 1><<<64, 256, 0, stream>>>(
        bufA, gates, bufB,
        wcat2, wcat2 + 2048*1024, whf + 2*2048*512, whb + 2*2048*512,
        fb + 2*2048, bbias + 2*2048, fInit + 2048, bInit + 2048, masks, hbuf, bar + 512,
        outH + 4*64*512, outC + 4*64*512);
    highway_kernel<1><<<dim3(256, 16), 256, 0, stream>>>(bufB, bufA, pj + 1024*1024, projB + 1024, out);
  } else {
    // fallback: in-scan input projection (no gates buffer needed)
    scan_kernel<512, 0><<<64, 256, 0, stream>>>(
        xbf, nullptr, bufA,
        wcat0, wcat0 + 2048*512, whf, whb,
        fb, bbias, fInit, bInit, masks, hbuf, bar,
        outH, outC);
    scan_kernel<1024, 0><<<64, 256, 0, stream>>>(
        bufA, nullptr, bufB,
        wcat1, wcat1 + 2048*1024, whf + 2048*512, whb + 2048*512,
        fb + 2048, bbias + 2048, fInit + 1024, bInit + 1024, masks, hbuf, bar + 256,
        outH + 2*64*512, outC + 2*64*512);
    highway_kernel<0><<<dim3(256, 16), 256, 0, stream>>>(bufB, bufA, pj, projB, nullptr);
    scan_kernel<1024, 0><<<64, 256, 0, stream>>>(
        bufA, nullptr, bufB,
        wcat2, wcat2 + 2048*1024, whf + 2*2048*512, whb + 2*2048*512,
        fb + 2*2048, bbias + 2*2048, fInit + 2048, bInit + 2048, masks, hbuf, bar + 512,
        outH + 4*64*512, outC + 4*64*512);
    highway_kernel<1><<<dim3(256, 16), 256, 0, stream>>>(bufB, bufA, pj + 1024*1024, projB + 1024, out);
  }
}

// Round 4
// 5992.390 us; speedup vs baseline: 3.3087x; 1.0856x over previous
//
#include <hip/hip_runtime.h>

typedef __attribute__((ext_vector_type(8))) short short8;
typedef __attribute__((ext_vector_type(4))) float f32x4;

#define MFMA_B16(a, b, c) __builtin_amdgcn_mfma_f32_16x16x32_bf16((a), (b), (c), 0, 0, 0)

#define TSTEPS 256
#define NBATCH 64
#define HID    512
#define NBLK   32   // blocks per direction
#define UB     16   // hidden units per block
#define HSLOT  (NBATCH * HID)  // shorts per h slot per dir

__device__ __forceinline__ unsigned short f2bf(float f) {
  unsigned int u = __float_as_uint(f);
  u += 0x7fffu + ((u >> 16) & 1u);
  return (unsigned short)(u >> 16);
}
__device__ __forceinline__ float bf2f(unsigned short s) {
  return __uint_as_float(((unsigned int)s) << 16);
}
__device__ __forceinline__ float sigm(float x) { return 1.0f / (1.0f + __expf(-x)); }
__device__ __forceinline__ float tanhf_(float x) {
  float xc = fminf(fmaxf(x, -15.0f), 15.0f);
  float e = __expf(2.0f * xc);
  return (e - 1.0f) / (e + 1.0f);
}

// 16B load from the coherent point (bypasses stale L1/L2), relaxed
__device__ __forceinline__ short8 ld_llc16(const unsigned short* p) {
  union { unsigned long long q[2]; short8 s; } u;
  unsigned long long* a = (unsigned long long*)p;
  u.q[0] = __hip_atomic_load(a,     __ATOMIC_RELAXED, __HIP_MEMORY_SCOPE_AGENT);
  u.q[1] = __hip_atomic_load(a + 1, __ATOMIC_RELAXED, __HIP_MEMORY_SCOPE_AGENT);
  return u.s;
}

__global__ void cvt_kernel(const float* __restrict__ src, unsigned short* __restrict__ dst, int n4) {
  int i = blockIdx.x * blockDim.x + threadIdx.x;
  int stride = gridDim.x * blockDim.x;
  for (; i < n4; i += stride) {
    f32x4 v = ((const f32x4*)src)[i];
    union { unsigned short u[4]; unsigned long long q; } o;
    o.u[0] = f2bf(v[0]); o.u[1] = f2bf(v[1]); o.u[2] = f2bf(v[2]); o.u[3] = f2bf(v[3]);
    ((unsigned long long*)dst)[i] = o.q;
  }
}

// gates_x precompute: gates[t][r][b] = sum_k wcat[r][k]*act[t*64+b][k] + bias(r)
// wcat rows 0..2047 = forward dir, 2048..4095 = backward dir (bias likewise).
// Grid: (16 row-blocks, 128 t-pairs), 256 threads. Each block: 2 timesteps,
// reusing every weight fragment for both (halves weight L2/LLC traffic).
template<int K>
__global__ __launch_bounds__(256)
void gates_gemm(const unsigned short* __restrict__ act,
                const unsigned short* __restrict__ wcat,
                const float* __restrict__ bias_f,
                const float* __restrict__ bias_b,
                unsigned short* __restrict__ gates)
{
  const int lane = threadIdx.x & 63;
  const int wave = threadIdx.x >> 6;
  const int n = lane & 15, kb = lane >> 4;
  const int t0 = blockIdx.y * 2;
  const int rbase = blockIdx.x * 256 + wave * 64;

  f32x4 acc[2][4][4];
  #pragma unroll
  for (int mt = 0; mt < 4; ++mt) {
    f32x4 bi;
    #pragma unroll
    for (int i = 0; i < 4; ++i) {
      int r = rbase + mt * 16 + kb * 4 + i;
      bi[i] = (r < 2048) ? bias_f[r] : bias_b[r - 2048];
    }
    #pragma unroll
    for (int nt = 0; nt < 4; ++nt) { acc[0][mt][nt] = bi; acc[1][mt][nt] = bi; }
  }

  const unsigned short* wrow  = wcat + (size_t)(rbase + n) * K + kb * 8;
  const unsigned short* arow0 = act + ((size_t)t0 * 64 + n) * K + kb * 8;
  const unsigned short* arow1 = arow0 + (size_t)64 * K;
  #pragma unroll 2
  for (int ks = 0; ks < K / 32; ++ks) {
    short8 af[4], b0[4], b1[4];
    #pragma unroll
    for (int mt = 0; mt < 4; ++mt) af[mt] = *(const short8*)(wrow + (size_t)mt * 16 * K + ks * 32);
    #pragma unroll
    for (int nt = 0; nt < 4; ++nt) {
      b0[nt] = *(const short8*)(arow0 + (size_t)nt * 16 * K + ks * 32);
      b1[nt] = *(const short8*)(arow1 + (size_t)nt * 16 * K + ks * 32);
    }
    #pragma unroll
    for (int mt = 0; mt < 4; ++mt)
      #pragma unroll
      for (int nt = 0; nt < 4; ++nt) {
        acc[0][mt][nt] = MFMA_B16(af[mt], b0[nt], acc[0][mt][nt]);
        acc[1][mt][nt] = MFMA_B16(af[mt], b1[nt], acc[1][mt][nt]);
      }
  }

  #pragma unroll
  for (int t2 = 0; t2 < 2; ++t2) {
    unsigned short* gbase = gates + (size_t)(t0 + t2) * 4096 * 64;
    #pragma unroll
    for (int mt = 0; mt < 4; ++mt)
      #pragma unroll
      for (int i = 0; i < 4; ++i) {
        int r = rbase + mt * 16 + kb * 4 + i;
        #pragma unroll
        for (int nt = 0; nt < 4; ++nt)
          gbase[(size_t)r * 64 + nt * 16 + n] = f2bf(acc[t2][mt][nt][i]);
      }
  }
}

// Persistent bidirectional LSTM layer scan.
// Grid: 64 blocks x 256 threads. Blocks 0..31 forward, 32..63 backward.
// Each block owns 16 hidden units (64 gate rows). Whh slice staged in LDS in
// exact MFMA B-fragment order. h exchanged via ws ping-pong through the
// coherent point; c stays in registers.
// Sync: per-block flag words on private 128B lines (no RMW contention).
// flag[dir][jb] >= t+1  means  h input for step t is published.
template<int DIN, int GXP>
__global__ __launch_bounds__(256, 1)
void scan_kernel(const unsigned short* __restrict__ act_in,
                 const unsigned short* __restrict__ gates,   // [T][4096][64] bf16
                 unsigned short* __restrict__ act_out,
                 const unsigned short* __restrict__ wih_f,
                 const unsigned short* __restrict__ wih_b,
                 const unsigned short* __restrict__ whh_f,
                 const unsigned short* __restrict__ whh_b,
                 const float* __restrict__ bias_f,
                 const float* __restrict__ bias_b,
                 const float* __restrict__ init_f,
                 const float* __restrict__ init_b,
                 const float* __restrict__ masks,
                 unsigned short* hb,          // [2 dirs][2 slots][HSLOT] bf16
                 unsigned int* flags,         // [2 dirs][NBLK] x 32 uints (128B lines)
                 float* out_h, float* out_c)
{
  const int bid  = blockIdx.x;
  const int dir  = bid >> 5;
  const int jb   = bid & (NBLK - 1);
  const int j0   = jb * UB;
  const int lane = threadIdx.x & 63;
  const int wave = threadIdx.x >> 6;
  const int n    = lane & 15;
  const int kb   = lane >> 4;
  const int u    = n & 7;
  const bool hif = (n >= 8);

  const unsigned short* wih = dir ? wih_b : wih_f;
  const unsigned short* whh = dir ? whh_b : whh_f;
  const float* bias = dir ? bias_b : bias_f;
  const float* init = dir ? init_b : init_f;
  unsigned int* fbase  = flags + dir * (NBLK * 32);
  unsigned int* myflag = fbase + jb * 32;
  unsigned short* hbd = hb + dir * (2 * HSLOT);
  float* oh = out_h + dir * (NBATCH * HID);
  float* oc = out_c + dir * (NBATCH * HID);

  // gate-row index per 16-wide n-tile. tiles: 0=[i|f] u0-7, 1=[i|f] u8-15,
  // 2=[g|o] u0-7, 3=[g|o] u8-15
  int wr[4];
  wr[0] = hif ? (512 + j0 + u) : (j0 + u);
  wr[1] = wr[0] + 8;
  wr[2] = wr[0] + 1024;
  wr[3] = wr[0] + 1032;

  float bb[4];
  const unsigned short* wihp[4];
  #pragma unroll
  for (int q = 0; q < 4; ++q) {
    bb[q] = bias[wr[q]];
    wihp[q] = wih + (size_t)wr[q] * DIN + kb * 8;
  }

  // Whh in LDS, pre-swizzled to per-lane fragment order:
  // wlds[(ks*4+q)*64 + lane] = Whh[growS(q, lane&15)][ks*32 + (lane>>4)*8 ..+7]
  __shared__ short8 wlds[16 * 4 * 64];             // 64 KB
  __shared__ unsigned short lsm[NBATCH * UB];      // 2 KB pack buffer

  for (int g = threadIdx.x; g < 4096; g += 256) {
    int n_ = g & 15, kb_ = (g >> 4) & 3, q_ = (g >> 6) & 3, ks_ = g >> 8;
    int grow = ((n_ >= 8) ? 512 : 0) + j0 + (n_ & 7) + (q_ & 1) * 8 + (q_ >> 1) * 1024;
    wlds[g] = *(const short8*)(whh + (size_t)grow * HID + ks_ * 32 + kb_ * 8);
  }

  // h0 init into slot 0 (this block's 64x16 slice), via agent-scope stores
  if (wave == 0) {
    union { unsigned short us[16]; unsigned long long q[4]; } iv;
    #pragma unroll
    for (int k = 0; k < 16; ++k) iv.us[k] = f2bf(init[j0 + k]);
    unsigned long long* hd = (unsigned long long*)(hbd + jb * (NBATCH * UB) + lane * UB);
    #pragma unroll
    for (int k = 0; k < 4; ++k)
      __hip_atomic_store(hd + k, iv.q[k], __ATOMIC_RELAXED, __HIP_MEMORY_SCOPE_AGENT);
  }
  float cs[2][4];
  #pragma unroll
  for (int uh = 0; uh < 2; ++uh)
    #pragma unroll
    for (int i = 0; i < 4; ++i)
      cs[uh][i] = init[512 + j0 + uh * 8 + u];

  __syncthreads();  // LDS staging + h0 done
  if (wave == 0) {
    asm volatile("s_waitcnt vmcnt(0)" ::: "memory");  // h0 at coherent point
    if (lane == 0)
      __hip_atomic_store(myflag, 1u, __ATOMIC_RELAXED, __HIP_MEMORY_SCOPE_AGENT);
  }

  f32x4 acc_e[4], acc_o[4];

  auto wih_load = [&](int tstep) {
    #pragma unroll
    for (int q = 0; q < 4; ++q) {
      acc_e[q] = (f32x4){bb[q], bb[q], bb[q], bb[q]};
      acc_o[q] = (f32x4){0.f, 0.f, 0.f, 0.f};
    }
    const int tt2 = dir ? (TSTEPS - 1 - tstep) : tstep;
    const unsigned short* arow = act_in + ((size_t)tt2 * NBATCH + wave * 16 + n) * DIN + kb * 8;
    #pragma unroll
    for (int kt = 0; kt < DIN / 32; kt += 2) {
      short8 a0 = *(const short8*)(arow + kt * 32);
      short8 a1 = *(const short8*)(arow + kt * 32 + 32);
      #pragma unroll
      for (int q = 0; q < 4; ++q) {
        acc_e[q] = MFMA_B16(a0, *(const short8*)(wihp[q] + kt * 32), acc_e[q]);
        acc_o[q] = MFMA_B16(a1, *(const short8*)(wihp[q] + kt * 32 + 32), acc_o[q]);
      }
    }
  };

  if (!GXP) wih_load(0);

  for (int t = 0; t < TSTEPS; ++t) {
    const int tt = dir ? (TSTEPS - 1 - t) : t;

    // prefetch: mask + gate pre-activations, issued before the poll so they
    // complete in its shadow
    f32x4 mk = *(const f32x4*)(masks + tt * NBATCH + wave * 16 + kb * 4);
    if (GXP) {
      const unsigned short* gb = gates + ((size_t)tt * 4096 + dir * 2048) * 64 + wave * 16 + kb * 4;
      #pragma unroll
      for (int q = 0; q < 4; ++q) {
        union { unsigned long long q8; unsigned short us[4]; } gv;
        gv.q8 = *(const unsigned long long*)(gb + (size_t)wr[q] * 64);
        acc_e[q] = (f32x4){bf2f(gv.us[0]), bf2f(gv.us[1]), bf2f(gv.us[2]), bf2f(gv.us[3])};
        acc_o[q] = (f32x4){0.f, 0.f, 0.f, 0.f};
      }
    }

    // wait for h(t-1): one 64-lane load covers all 32 flags (2 lanes/line)
    if (wave == 0) {
      const unsigned int tgt = t + 1;
      unsigned int* fp = fbase + (lane & 31) * 32;
      while (!__all((int)(__hip_atomic_load(fp, __ATOMIC_RELAXED, __HIP_MEMORY_SCOPE_AGENT) >= tgt)))
        __builtin_amdgcn_s_sleep(1);
    }
    __syncthreads();

    // recurrent part: h(t-1) @ Whh_slice; h from coherent point, Whh from LDS
    {
      const unsigned short* hrow = hbd + (t & 1) * HSLOT
                                 + (kb >> 1) * 1024 + (kb & 1) * 8 + (wave * 16 + n) * UB;
      short8 hf[16];
      #pragma unroll
      for (int ks = 0; ks < 16; ++ks) hf[ks] = ld_llc16(hrow + ks * 2048);
      #pragma unroll
      for (int ks = 0; ks < 16; ++ks) {
        f32x4* ac = (ks & 1) ? acc_o : acc_e;
        #pragma unroll
        for (int q = 0; q < 4; ++q)
          ac[q] = MFMA_B16(hf[ks], wlds[(ks * 4 + q) * 64 + lane], ac[q]);
      }
    }

    #pragma unroll
    for (int uh = 0; uh < 2; ++uh) {
      f32x4 aif = acc_e[uh] + acc_o[uh];
      f32x4 ago = acc_e[2 + uh] + acc_o[2 + uh];
      f32x4 oif, ogo;
      #pragma unroll
      for (int r = 0; r < 4; ++r) {
        oif[r] = __shfl_xor(aif[r], 8, 64);
        ogo[r] = __shfl_xor(ago[r], 8, 64);
      }
      #pragma unroll
      for (int i = 0; i < 4; ++i) {
        float vi = hif ? oif[i] : aif[i];
        float vf = hif ? aif[i] : oif[i];
        float vg = hif ? ogo[i] : ago[i];
        float vo = hif ? ago[i] : ogo[i];
        float cn = (sigm(vf) * cs[uh][i] + sigm(vi) * tanhf_(vg)) * mk[i];
        float hvv = sigm(vo) * tanhf_(cn) * mk[i];
        cs[uh][i] = cn;
        if (!hif) {
          const int b = wave * 16 + kb * 4 + i;
          lsm[b * UB + uh * 8 + u] = f2bf(hvv);
          if (t == TSTEPS - 1) {
            oh[b * HID + j0 + uh * 8 + u] = hvv;
            oc[b * HID + j0 + uh * 8 + u] = cn;
          }
        }
      }
    }

    __syncthreads();  // drains all waves' LDS writes

    // wave 0: publish h slice (agent stores -> vmcnt -> flag), then act_out
    if (wave == 0) {
      const unsigned long long* lq = (const unsigned long long*)lsm;
      unsigned long long q0 = lq[lane * 4 + 0];
      unsigned long long q1 = lq[lane * 4 + 1];
      unsigned long long q2 = lq[lane * 4 + 2];
      unsigned long long q3 = lq[lane * 4 + 3];
      if (t + 1 < TSTEPS) {
        unsigned short* hnxt = hbd + ((t + 1) & 1) * HSLOT;
        unsigned long long* hd = (unsigned long long*)(hnxt + jb * (NBATCH * UB) + lane * UB);
        __hip_atomic_store(hd + 0, q0, __ATOMIC_RELAXED, __HIP_MEMORY_SCOPE_AGENT);
        __hip_atomic_store(hd + 1, q1, __ATOMIC_RELAXED, __HIP_MEMORY_SCOPE_AGENT);
        __hip_atomic_store(hd + 2, q2, __ATOMIC_RELAXED, __HIP_MEMORY_SCOPE_AGENT);
        __hip_atomic_store(hd + 3, q3, __ATOMIC_RELAXED, __HIP_MEMORY_SCOPE_AGENT);
        asm volatile("s_waitcnt vmcnt(0)" ::: "memory");
        if (lane == 0)
          __hip_atomic_store(myflag, (unsigned int)(t + 2), __ATOMIC_RELAXED, __HIP_MEMORY_SCOPE_AGENT);
      }
      union { unsigned long long q[2]; short8 s; } p0, p1;
      p0.q[0] = q0; p0.q[1] = q1; p1.q[0] = q2; p1.q[1] = q3;
      short8* ar = (short8*)(act_out + ((size_t)tt * NBATCH + lane) * (2 * HID) + dir * HID + j0);
      ar[0] = p0.s;
      ar[1] = p1.s;
    }

    if (!GXP && t + 1 < TSTEPS) wih_load(t + 1);
  }
}

// Highway gate: g = sigmoid(raw @ projW^T + projb); out = g*raw + (1-g)*inp
// FINAL=0: write bf16 in-place over inp. FINAL=1: write fp32 to outf.
template<int FINAL>
__global__ __launch_bounds__(256)
void highway_kernel(const unsigned short* __restrict__ raw,
                    unsigned short* __restrict__ inp,
                    const unsigned short* __restrict__ pw,
                    const float* __restrict__ pb,
                    float* __restrict__ outf)
{
  const int lane = threadIdx.x & 63;
  const int wave = threadIdx.x >> 6;
  const int n = lane & 15, kb = lane >> 4;
  const int r0 = blockIdx.x * 64 + wave * 16;
  const int c0 = blockIdx.y * 64;

  f32x4 acc[4];
  #pragma unroll
  for (int nt = 0; nt < 4; ++nt) {
    float b = pb[c0 + nt * 16 + n];
    acc[nt] = (f32x4){b, b, b, b};
  }
  const unsigned short* arow = raw + (r0 + n) * 1024 + kb * 8;
  #pragma unroll 4
  for (int kt = 0; kt < 32; ++kt) {
    short8 a = *(const short8*)(arow + kt * 32);
    #pragma unroll
    for (int nt = 0; nt < 4; ++nt) {
      short8 b = *(const short8*)(pw + (c0 + nt * 16 + n) * 1024 + kt * 32 + kb * 8);
      acc[nt] = MFMA_B16(a, b, acc[nt]);
    }
  }
  #pragma unroll
  for (int nt = 0; nt < 4; ++nt) {
    #pragma unroll
    for (int i = 0; i < 4; ++i) {
      int row = r0 + kb * 4 + i;
      int col = c0 + nt * 16 + n;
      float g = sigm(acc[nt][i]);
      float rv = bf2f(raw[row * 1024 + col]);
      float iv = bf2f(inp[row * 1024 + col]);
      float ov = g * rv + (1.0f - g) * iv;
      if (FINAL) outf[row * 1024 + col] = ov;
      else       inp[row * 1024 + col] = f2bf(ov);
    }
  }
}

extern "C" void kernel_launch(void* const* d_in, const int* in_sizes, int n_in,
                              void* d_out, int out_size, void* d_ws, size_t ws_size,
                              hipStream_t stream) {
  const float* x     = (const float*)d_in[0];
  const float* masks = (const float*)d_in[1];
  const float* fWih0 = (const float*)d_in[2];
  const float* fWihR = (const float*)d_in[3];
  const float* fWhh  = (const float*)d_in[4];
  const float* fb    = (const float*)d_in[5];
  const float* bWih0 = (const float*)d_in[6];
  const float* bWihR = (const float*)d_in[7];
  const float* bWhh  = (const float*)d_in[8];
  const float* bbias = (const float*)d_in[9];
  const float* fInit = (const float*)d_in[10];
  const float* bInit = (const float*)d_in[11];
  const float* projW = (const float*)d_in[12];
  const float* projB = (const float*)d_in[13];
  float* out = (float*)d_out;

  char* ws = (char*)d_ws;
  unsigned short* bufA  = (unsigned short*)(ws + 0);           // 33,554,432
  unsigned short* bufB  = (unsigned short*)(ws + 33554432);    // 33,554,432
  unsigned short* xbf   = (unsigned short*)(ws + 67108864);    // 16,777,216
  unsigned short* wcat0 = (unsigned short*)(ws + 83886080);    //  4,194,304 [4096][512]
  unsigned short* wcat1 = (unsigned short*)(ws + 88080384);    //  8,388,608 [4096][1024]
  unsigned short* wcat2 = (unsigned short*)(ws + 96468992);    //  8,388,608
  unsigned short* whf   = (unsigned short*)(ws + 104857600);   //  6,291,456
  unsigned short* whb   = (unsigned short*)(ws + 111149056);   //  6,291,456
  unsigned short* pj    = (unsigned short*)(ws + 117440512);   //  4,194,304
  unsigned short* hbuf  = (unsigned short*)(ws + 121634816);   //    262,144
  unsigned int*   bar   = (unsigned int*)(ws + 121896960);     //     24,576 (3 layers x 8KB flags)
  unsigned short* gates = (unsigned short*)(ws + 121921536);   // 134,217,728 [256][4096][64]
  const bool gx = ws_size >= 256139264ull;

  hipMemsetAsync(bar, 0, 24576, stream);

  cvt_kernel<<<1024, 256, 0, stream>>>(x,     xbf,   (256*64*512)  / 4);
  cvt_kernel<<<1024, 256, 0, stream>>>(fWih0, wcat0,              (2048*512)  / 4);
  cvt_kernel<<<1024, 256, 0, stream>>>(bWih0, wcat0 + 2048*512,   (2048*512)  / 4);
  cvt_kernel<<<1024, 256, 0, stream>>>(fWihR,             wcat1,             (2048*1024) / 4);
  cvt_kernel<<<1024, 256, 0, stream>>>(bWihR,             wcat1 + 2048*1024, (2048*1024) / 4);
  cvt_kernel<<<1024, 256, 0, stream>>>(fWihR + 2048*1024, wcat2,             (2048*1024) / 4);
  cvt_kernel<<<1024, 256, 0, stream>>>(bWihR + 2048*1024, wcat2 + 2048*1024, (2048*1024) / 4);
  cvt_kernel<<<1024, 256, 0, stream>>>(fWhh,  whf,   (3*2048*512)  / 4);
  cvt_kernel<<<1024, 256, 0, stream>>>(bWhh,  whb,   (3*2048*512)  / 4);
  cvt_kernel<<<1024, 256, 0, stream>>>(projW, pj,    (2*1024*1024) / 4);

  float* outH = out + 16777216;
  float* outC = out + 16777216 + 6*64*512;

  if (gx) {
    // layer 0
    gates_gemm<512><<<dim3(16, 128), 256, 0, stream>>>(xbf, wcat0, fb, bbias, gates);
    scan_kernel<512, 1><<<64, 256, 0, stream>>>(
        xbf, gates, bufA,
        wcat0, wcat0 + 2048*512, whf, whb,
        fb, bbias, fInit, bInit, masks, hbuf, bar,
        outH, outC);
    // layer 1
    gates_gemm<1024><<<dim3(16, 128), 256, 0, stream>>>(bufA, wcat1, fb + 2048, bbias + 2048, gates);
    scan_kernel<1024, 1><<<64, 256, 0, stream>>>(
        bufA, gates, bufB,
        wcat1, wcat1 + 2048*1024, whf + 2048*512, whb + 2048*512,
        fb + 2048, bbias + 2048, fInit + 1024, bInit + 1024, masks, hbuf, bar + 2048,
        outH + 2*64*512, outC + 2*64*512);
    highway_kernel<0><<<dim3(256, 16), 256, 0, stream>>>(bufB, bufA, pj, projB, nullptr);
    // layer 2
    gates_gemm<1024><<<dim3(16, 128), 256, 0, stream>>>(bufA, wcat2, fb + 2*2048, bbias + 2*2048, gates);
    scan_kernel<1024, 1><<<64, 256, 0, stream>>>(
        bufA, gates, bufB,
        wcat2, wcat2 + 2048*1024, whf + 2*2048*512, whb + 2*2048*512,
        fb + 2*2048, bbias + 2*2048, fInit + 2048, bInit + 2048, masks, hbuf, bar + 4096,
        outH + 4*64*512, outC + 4*64*512);
    highway_kernel<1><<<dim3(256, 16), 256, 0, stream>>>(bufB, bufA, pj + 1024*1024, projB + 1024, out);
  } else {
    // fallback: in-scan input projection (no gates buffer needed)
    scan_kernel<512, 0><<<64, 256, 0, stream>>>(
        xbf, nullptr, bufA,
        wcat0, wcat0 + 2048*512, whf, whb,
        fb, bbias, fInit, bInit, masks, hbuf, bar,
        outH, outC);
    scan_kernel<1024, 0><<<64, 256, 0, stream>>>(
        bufA, nullptr, bufB,
        wcat1, wcat1 + 2048*1024, whf + 2048*512, whb + 2048*512,
        fb + 2048, bbias + 2048, fInit + 1024, bInit + 1024, masks, hbuf, bar + 2048,
        outH + 2*64*512, outC + 2*64*512);
    highway_kernel<0><<<dim3(256, 16), 256, 0, stream>>>(bufB, bufA, pj, projB, nullptr);
    scan_kernel<1024, 0><<<64, 256, 0, stream>>>(
        bufA, nullptr, bufB,
        wcat2, wcat2 + 2048*1024, whf + 2*2048*512, whb + 2*2048*512,
        fb + 2*2048, bbias + 2*2048, fInit + 2048, bInit + 2048, masks, hbuf, bar + 4096,
        outH + 4*64*512, outC + 4*64*512);
    highway_kernel<1><<<dim3(256, 16), 256, 0, stream>>>(bufB, bufA, pj + 1024*1024, projB + 1024, out);
  }
}